// Round 10
// baseline (303.646 us; speedup 1.0000x reference)
//
#include <hip/hip_runtime.h>
#include <hip/hip_bf16.h>

typedef __attribute__((ext_vector_type(8))) short short8;
typedef __attribute__((ext_vector_type(4))) short short4v;
typedef __attribute__((ext_vector_type(4))) float f32x4;

__device__ __forceinline__ short f2bf(float f) {
  union { __hip_bfloat16 h; short s; } u;
  u.h = __float2bfloat16(f);
  return u.s;
}

#define SCHED_FENCE() __builtin_amdgcn_sched_barrier(0)
#define EPS 68   // epilogue f32 row stride

// C[512, N] = A_bf16[512, K] * W_f32[N, K]^T + bias.  BN=64, 8 waves,
// wave w owns rows [w*64, w*64+64); all waves share the 64-row W panel.
// Per iter (BK=32): A(b) -> regs (4 short8, L2-resident); W staged
// global f32 -> regs (1 f32x4/thread, issued 2 iters ahead) -> cvt bf16 ->
// LDS dbuf (4KB/tile). ONE raw s_barrier per iter, preceded only by
// lgkmcnt(0) -- NO vmcnt drain, so the compiler's counted vmcnt(1) before
// the first MFMA is the only global wait (leaves W(b+2) in flight).
// LDS/iter = 32KB read + 4KB write ~= MFMA time -> balanced.
// W LDS tile [64 rows][32 k] bf16, 16B-slot XOR swizzle: slot16 ^= row&3
// (write and read side) -> even 8-lane spread per bank cluster.
template<int K>
__device__ __forceinline__ void gemm_bf(
    const short* __restrict__ A,
    const float* __restrict__ W,
    const float* __restrict__ bias,
    float* __restrict__ C,
    int N, int n0, char* smem)
{
  constexpr int NT = K / 32;
  short* wl = (short*)smem;            // 2 bufs x 2048 shorts (4KB)

  const int t   = threadIdx.x;
  const int w   = t >> 6;
  const int l   = t & 63;
  const int l16 = l & 15;
  const int lq  = l >> 4;

  // W stage addressing: thread t -> row r=t>>3, f32 piece p=t&7 (k=4p..4p+3)
  const int r = t >> 3, p = t & 7;
  const float* wp = W + (size_t)(n0 + r) * K + p * 4;
  const int woff = r * 32 + ((((p >> 1) ^ (r & 3)) << 3) + ((p & 1) << 2));
  // read: lane wants row=nf*16+l16, k=lq*8..: swizzled 16B slot = lq^(row&3)
  const int roff = l16 * 32 + ((lq ^ (l16 & 3)) << 3);   // + nf*512

  const short* ap = A + (size_t)(w * 64 + l16) * K + lq * 8;

  f32x4 acc[4][4];
  #pragma unroll
  for (int i = 0; i < 4; ++i)
    #pragma unroll
    for (int j = 0; j < 4; ++j) {
      f32x4 z = {0.f, 0.f, 0.f, 0.f};
      acc[i][j] = z;
    }

  auto commit = [&](const f32x4& wc, int buf) {
    short4v cv;
    #pragma unroll
    for (int i = 0; i < 4; ++i) cv[i] = f2bf(wc[i]);
    *(short4v*)(wl + buf * 2048 + woff) = cv;
  };

  // prologue: W(0) -> buf0; W(1) stays in regs
  f32x4 wA = *(const f32x4*)(wp);
  f32x4 wB = *(const f32x4*)(wp + 32);
  commit(wA, 0);
  asm volatile("s_waitcnt lgkmcnt(0)" ::: "memory");
  SCHED_FENCE();
  __builtin_amdgcn_s_barrier();

  auto iter = [&](int b, f32x4& wCom, f32x4& wLd) {
    SCHED_FENCE();
    short8 a[4];
    #pragma unroll
    for (int mf = 0; mf < 4; ++mf)
      a[mf] = *(const short8*)(ap + (size_t)mf * 16 * K + b * 32);
    if (b + 2 < NT) wLd = *(const f32x4*)(wp + (b + 2) * 32);
    SCHED_FENCE();                       // pin issue-early
    const short* lb = wl + (b & 1) * 2048;
    #pragma unroll
    for (int nf = 0; nf < 4; ++nf) {
      short8 bb = *(const short8*)(lb + nf * 512 + roff);
      #pragma unroll
      for (int mf = 0; mf < 4; ++mf)
        acc[mf][nf] = __builtin_amdgcn_mfma_f32_16x16x32_bf16(a[mf], bb, acc[mf][nf], 0, 0, 0);
    }
    if (b + 1 < NT) commit(wCom, (b + 1) & 1);
    asm volatile("s_waitcnt lgkmcnt(0)" ::: "memory");
    SCHED_FENCE();
    __builtin_amdgcn_s_barrier();        // raw: no vmcnt drain
  };

  for (int b = 0; b < NT; b += 2) {
    iter(b,     wB, wA);                 // commit W(b+1), load W(b+2)
    iter(b + 1, wA, wB);                 // commit W(b+2), load W(b+3)
  }

  // ---- epilogue: per-wave LDS transpose -> full-line f32x4 stores ----
  // acc layout: col = nf*16 + l16, row = mf*16 + lq*4 + rr  [m89]
  float bvv[4];
  #pragma unroll
  for (int nf = 0; nf < 4; ++nf) bvv[nf] = bias[n0 + nf * 16 + l16];

  float* ep = (float*)(smem) + w * 16 * EPS;
  const int rr = lq;
  const int cc = l16 * 4;
  #pragma unroll
  for (int mf = 0; mf < 4; ++mf) {
    #pragma unroll
    for (int nf = 0; nf < 4; ++nf)
      #pragma unroll
      for (int rg = 0; rg < 4; ++rg)
        ep[(lq * 4 + rg) * EPS + nf * 16 + l16] = acc[mf][nf][rg] + bvv[nf];
    #pragma unroll
    for (int i = 0; i < 4; ++i) {
      f32x4 vv = *(const f32x4*)&ep[(i * 4 + rr) * EPS + cc];
      *(f32x4*)&C[(size_t)(w * 64 + mf * 16 + i * 4 + rr) * N + n0 + cc] = vv;
    }
  }
}

__global__ __launch_bounds__(512, 4) void gru_gemms_kernel(
    const short* __restrict__ xbf, const short* __restrict__ hbf,
    const float* __restrict__ W_ih, const float* __restrict__ W_hh,
    const float* __restrict__ b_ih, const float* __restrict__ b_hh,
    float* __restrict__ gi, float* __restrict__ gh)
{
  __shared__ __align__(16) char smem[34816];   // max(8KB W dbuf, epilogue)
  const bool second = blockIdx.x >= 96;
  const int nb = second ? (int)blockIdx.x - 96 : (int)blockIdx.x;
  if (second)
    gemm_bf<2048>(hbf, W_hh, b_hh, gh, 6144, nb * 64, smem);
  else
    gemm_bf<1024>(xbf, W_ih, b_ih, gi, 6144, nb * 64, smem);
}

__global__ __launch_bounds__(512, 4) void logits_kernel(
    const short* __restrict__ hnbf, const float* __restrict__ fc_W,
    const float* __restrict__ fc_b, float* __restrict__ out)
{
  __shared__ __align__(16) char smem[34816];
  gemm_bf<2048>(hnbf, fc_W, fc_b, out, 32000, (int)blockIdx.x * 64, smem);
}

__global__ void prep_kernel(const int* __restrict__ idx,
                            const float* __restrict__ hid,
                            const float* __restrict__ emb,
                            short* __restrict__ xbf, short* __restrict__ hbf)
{
  int i = blockIdx.x * blockDim.x + threadIdx.x;
  const int NX = 512 * 1024 / 4;
  const int NH = 512 * 2048 / 4;
  if (i < NX) {
    int b = i >> 8;
    int c = (i & 255) << 2;
    int row = idx[b];
    f32x4 v = *(const f32x4*)(emb + (size_t)row * 1024 + c);
    short4v o;
    #pragma unroll
    for (int j = 0; j < 4; ++j) o[j] = f2bf(v[j]);
    *(short4v*)(xbf + (size_t)b * 1024 + c) = o;
  } else if (i < NX + NH) {
    int j2 = i - NX;
    f32x4 v = *(const f32x4*)(hid + (size_t)j2 * 4);
    short4v o;
    #pragma unroll
    for (int j = 0; j < 4; ++j) o[j] = f2bf(v[j]);
    *(short4v*)(hbf + (size_t)j2 * 4) = o;
  }
}

__global__ void gates_kernel(const float* __restrict__ gi,
                             const float* __restrict__ gh,
                             const float* __restrict__ hid,
                             float* __restrict__ hnew,
                             short* __restrict__ hnbf)
{
  int i = blockIdx.x * blockDim.x + threadIdx.x;
  int b = i >> 9;
  int c = (i & 511) << 2;
  size_t gbase = (size_t)b * 6144 + c;
  f32x4 gir = *(const f32x4*)(gi + gbase);
  f32x4 giz = *(const f32x4*)(gi + gbase + 2048);
  f32x4 gin = *(const f32x4*)(gi + gbase + 4096);
  f32x4 ghr = *(const f32x4*)(gh + gbase);
  f32x4 ghz = *(const f32x4*)(gh + gbase + 2048);
  f32x4 ghn = *(const f32x4*)(gh + gbase + 4096);
  f32x4 hv  = *(const f32x4*)(hid + (size_t)b * 2048 + c);
  f32x4 hn;
  short4v hb;
  #pragma unroll
  for (int j = 0; j < 4; ++j) {
    float r = 1.f / (1.f + __expf(-(gir[j] + ghr[j])));
    float z = 1.f / (1.f + __expf(-(giz[j] + ghz[j])));
    float n = tanhf(gin[j] + r * ghn[j]);
    float o = (1.f - z) * n + z * hv[j];
    hn[j] = o;
    hb[j] = f2bf(o);
  }
  *(f32x4*)(hnew + (size_t)b * 2048 + c) = hn;
  *(short4v*)(hnbf + (size_t)b * 2048 + c) = hb;
}

extern "C" void kernel_launch(void* const* d_in, const int* in_sizes, int n_in,
                              void* d_out, int out_size, void* d_ws, size_t ws_size,
                              hipStream_t stream)
{
  const int*   idx   = (const int*)d_in[0];
  const float* hid   = (const float*)d_in[1];
  const float* emb   = (const float*)d_in[2];
  const float* W_ih  = (const float*)d_in[3];
  const float* W_hh  = (const float*)d_in[4];
  const float* b_ih  = (const float*)d_in[5];
  const float* b_hh  = (const float*)d_in[6];
  const float* fc_W  = (const float*)d_in[7];
  const float* fc_b  = (const float*)d_in[8];
  float* out = (float*)d_out;

  char* ws = (char*)d_ws;
  short* xbf  = (short*)(ws);
  short* hbf  = (short*)(ws + 1048576);
  short* hnbf = (short*)(ws + 3145728);
  float* gi   = (float*)(ws + 5242880);
  float* gh   = (float*)(ws + 17825792);

  prep_kernel<<<1536, 256, 0, stream>>>(idx, hid, emb, xbf, hbf);
  gru_gemms_kernel<<<192, 512, 0, stream>>>(xbf, hbf, W_ih, W_hh, b_ih, b_hh, gi, gh);
  gates_kernel<<<1024, 256, 0, stream>>>(gi, gh, hid, out + (size_t)512 * 32000, hnbf);
  // 500 blocks x BN=64: W panel read once; ~2 blocks/CU
  logits_kernel<<<500, 512, 0, stream>>>(hnbf, fc_W, fc_b, out);
}

// Round 11
// 275.670 us; speedup vs baseline: 1.1015x; 1.1015x over previous
//
#include <hip/hip_runtime.h>
#include <hip/hip_bf16.h>

typedef __attribute__((ext_vector_type(8))) short short8;
typedef __attribute__((ext_vector_type(4))) short short4v;
typedef __attribute__((ext_vector_type(4))) float f32x4;

__device__ __forceinline__ short f2bf(float f) {
  union { __hip_bfloat16 h; short s; } u;
  u.h = __float2bfloat16(f);
  return u.s;
}

// async 16B global->LDS DMA: LDS dst = wave-uniform base + lane*16 (m104);
// global src per-lane.
__device__ __forceinline__ void gll16(const void* g, void* l) {
  __builtin_amdgcn_global_load_lds(
      (const __attribute__((address_space(1))) void*)g,
      (__attribute__((address_space(3))) void*)l, 16, 0, 0);
}

#define SCHED_FENCE() __builtin_amdgcn_sched_barrier(0)
#define EPS 68   // epilogue f32 row stride

// C[512, N] = A_bf16[512, K] * W_f32[N, K]^T + bias.   BN = 64.
// 8 waves; wave w owns rows [w*64..w*64+64); all waves share the W panel.
// Per iter (BK=32):
//   wait vmcnt(1)            -- drains A(b)+W(b), leaves W(b+2) in flight
//   raw s_barrier            -- W(b) visible to all (no ds_writes -> no lgkm)
//   issue A(b+1) -> regs     -- L2-resident bf16, 1-iter flight
//   consume(b): 8 swizzled ds_read_b128 of W + cvt + 32 MFMA
//   issue W(b+3) -> DMA ring slot (b+3)&3   -- 2-iter flight, race-free
// W f32 tile [64][32] rows=128B; DMA writes phys-linear; source k-piece
// (l&7)^(l>>3) realizes lds[r][s] = glob[r][s^(r&7)]; read slot =
// (2*lq+d)^(row&7)  -> R3-verified conflict-free pattern.
template<int K>
__device__ __forceinline__ void gemm_dma(
    const short* __restrict__ A,
    const float* __restrict__ W,
    const float* __restrict__ bias,
    float* __restrict__ C,
    int N, int n0, char* smem)
{
  constexpr int NT = K / 32;

  const int t   = threadIdx.x;
  const int w   = t >> 6;
  const int l   = t & 63;
  const int l16 = l & 15;
  const int lq  = l >> 4;

  f32x4 acc[4][4];
  #pragma unroll
  for (int i = 0; i < 4; ++i)
    #pragma unroll
    for (int j = 0; j < 4; ++j) {
      f32x4 z = {0.f, 0.f, 0.f, 0.f};
      acc[i][j] = z;
    }

  // DMA source: row r = w*8 + (l>>3), source k-piece = (l&7)^(l>>3)
  const float* wsrc = W + (size_t)(n0 + w * 8 + (l >> 3)) * K
                        + (((l & 7) ^ (l >> 3)) << 2);
  // DMA dst (wave-uniform): slot base + w*1024; HW adds lane*16
  auto issueW = [&](int bi) {
    gll16(wsrc + (bi << 5), smem + (bi & 3) * 8192 + w * 1024);
  };

  const short* ap = A + (size_t)(w * 64 + l16) * K + lq * 8;
  auto issueA = [&](int bi, short8 (&a)[4]) {
    #pragma unroll
    for (int mf = 0; mf < 4; ++mf)
      a[mf] = *(const short8*)(ap + (size_t)mf * 16 * K + (bi << 5));
  };

  auto consume = [&](int bi, short8 (&a)[4]) {
    const char* wb = smem + (bi & 3) * 8192;
    const int x = l16 & 7;
    #pragma unroll
    for (int nf = 0; nf < 4; ++nf) {
      const int row = nf * 16 + l16;
      f32x4 u = *(const f32x4*)(wb + row * 128 + (((2 * lq)     ^ x) << 4));
      f32x4 v = *(const f32x4*)(wb + row * 128 + (((2 * lq + 1) ^ x) << 4));
      short8 bb;
      #pragma unroll
      for (int i = 0; i < 4; ++i) { bb[i] = f2bf(u[i]); bb[i + 4] = f2bf(v[i]); }
      #pragma unroll
      for (int mf = 0; mf < 4; ++mf)
        acc[mf][nf] = __builtin_amdgcn_mfma_f32_16x16x32_bf16(a[mf], bb, acc[mf][nf], 0, 0, 0);
    }
  };

  short8 aA[4], aB[4];
  issueA(0, aA);                 // oldest in queue (so steady count works)
  issueW(0); issueW(1); issueW(2);

  auto step = [&](int b, short8 (&aCur)[4], short8 (&aNxt)[4]) {
    if (b + 4 <= NT) { asm volatile("s_waitcnt vmcnt(1)" ::: "memory"); }
    else             { asm volatile("s_waitcnt vmcnt(0)" ::: "memory"); }
    SCHED_FENCE();
    __builtin_amdgcn_s_barrier();       // raw: no ds_writes, no lgkm drain
    SCHED_FENCE();
    if (b + 1 < NT) issueA(b + 1, aNxt);
    SCHED_FENCE();                      // pin A-issue before consume
    consume(b, aCur);
    SCHED_FENCE();                      // pin W-issue after consume
    if (b + 3 < NT) issueW(b + 3);      // slot (b-1)&3: all waves done with it
  };

  for (int b = 0; b < NT; b += 2) {     // NT even (32 or 64)
    step(b,     aA, aB);
    step(b + 1, aB, aA);
  }
  __syncthreads();                       // before aliasing ring as epilogue

  // ---- epilogue: per-wave LDS transpose -> full-line f32x4 stores ----
  // acc layout: col = nf*16 + l16, row = mf*16 + lq*4 + r  [m89]
  float bvv[4];
  #pragma unroll
  for (int nf = 0; nf < 4; ++nf) bvv[nf] = bias[n0 + nf * 16 + l16];

  float* ep = (float*)(smem) + w * 16 * EPS;
  const int rr = lq;
  const int cc = l16 * 4;
  #pragma unroll
  for (int mf = 0; mf < 4; ++mf) {
    #pragma unroll
    for (int nf = 0; nf < 4; ++nf)
      #pragma unroll
      for (int r = 0; r < 4; ++r)
        ep[(lq * 4 + r) * EPS + nf * 16 + l16] = acc[mf][nf][r] + bvv[nf];
    #pragma unroll
    for (int i = 0; i < 4; ++i) {
      f32x4 vv = *(const f32x4*)&ep[(i * 4 + rr) * EPS + cc];
      *(f32x4*)&C[(size_t)(w * 64 + mf * 16 + i * 4 + rr) * N + n0 + cc] = vv;
    }
  }
}

__global__ __launch_bounds__(512, 4) void gru_gemms_kernel(
    const short* __restrict__ xbf, const short* __restrict__ hbf,
    const float* __restrict__ W_ih, const float* __restrict__ W_hh,
    const float* __restrict__ b_ih, const float* __restrict__ b_hh,
    float* __restrict__ gi, float* __restrict__ gh)
{
  __shared__ __align__(16) char smem[34816];   // max(4*8KB ring, epilogue)
  const bool second = blockIdx.x >= 96;
  const int nb = second ? (int)blockIdx.x - 96 : (int)blockIdx.x;
  if (second)
    gemm_dma<2048>(hbf, W_hh, b_hh, gh, 6144, nb * 64, smem);
  else
    gemm_dma<1024>(xbf, W_ih, b_ih, gi, 6144, nb * 64, smem);
}

__global__ __launch_bounds__(512, 4) void logits_kernel(
    const short* __restrict__ hnbf, const float* __restrict__ fc_W,
    const float* __restrict__ fc_b, float* __restrict__ out)
{
  __shared__ __align__(16) char smem[34816];
  gemm_dma<2048>(hnbf, fc_W, fc_b, out, 32000, (int)blockIdx.x * 64, smem);
}

__global__ void prep_kernel(const int* __restrict__ idx,
                            const float* __restrict__ hid,
                            const float* __restrict__ emb,
                            short* __restrict__ xbf, short* __restrict__ hbf)
{
  int i = blockIdx.x * blockDim.x + threadIdx.x;
  const int NX = 512 * 1024 / 4;
  const int NH = 512 * 2048 / 4;
  if (i < NX) {
    int b = i >> 8;
    int c = (i & 255) << 2;
    int row = idx[b];
    f32x4 v = *(const f32x4*)(emb + (size_t)row * 1024 + c);
    short4v o;
    #pragma unroll
    for (int j = 0; j < 4; ++j) o[j] = f2bf(v[j]);
    *(short4v*)(xbf + (size_t)b * 1024 + c) = o;
  } else if (i < NX + NH) {
    int j2 = i - NX;
    f32x4 v = *(const f32x4*)(hid + (size_t)j2 * 4);
    short4v o;
    #pragma unroll
    for (int j = 0; j < 4; ++j) o[j] = f2bf(v[j]);
    *(short4v*)(hbf + (size_t)j2 * 4) = o;
  }
}

__global__ void gates_kernel(const float* __restrict__ gi,
                             const float* __restrict__ gh,
                             const float* __restrict__ hid,
                             float* __restrict__ hnew,
                             short* __restrict__ hnbf)
{
  int i = blockIdx.x * blockDim.x + threadIdx.x;
  int b = i >> 9;
  int c = (i & 511) << 2;
  size_t gbase = (size_t)b * 6144 + c;
  f32x4 gir = *(const f32x4*)(gi + gbase);
  f32x4 giz = *(const f32x4*)(gi + gbase + 2048);
  f32x4 gin = *(const f32x4*)(gi + gbase + 4096);
  f32x4 ghr = *(const f32x4*)(gh + gbase);
  f32x4 ghz = *(const f32x4*)(gh + gbase + 2048);
  f32x4 ghn = *(const f32x4*)(gh + gbase + 4096);
  f32x4 hv  = *(const f32x4*)(hid + (size_t)b * 2048 + c);
  f32x4 hn;
  short4v hb;
  #pragma unroll
  for (int j = 0; j < 4; ++j) {
    float r = 1.f / (1.f + __expf(-(gir[j] + ghr[j])));
    float z = 1.f / (1.f + __expf(-(giz[j] + ghz[j])));
    float n = tanhf(gin[j] + r * ghn[j]);
    float o = (1.f - z) * n + z * hv[j];
    hn[j] = o;
    hb[j] = f2bf(o);
  }
  *(f32x4*)(hnew + (size_t)b * 2048 + c) = hn;
  *(short4v*)(hnbf + (size_t)b * 2048 + c) = hb;
}

extern "C" void kernel_launch(void* const* d_in, const int* in_sizes, int n_in,
                              void* d_out, int out_size, void* d_ws, size_t ws_size,
                              hipStream_t stream)
{
  const int*   idx   = (const int*)d_in[0];
  const float* hid   = (const float*)d_in[1];
  const float* emb   = (const float*)d_in[2];
  const float* W_ih  = (const float*)d_in[3];
  const float* W_hh  = (const float*)d_in[4];
  const float* b_ih  = (const float*)d_in[5];
  const float* b_hh  = (const float*)d_in[6];
  const float* fc_W  = (const float*)d_in[7];
  const float* fc_b  = (const float*)d_in[8];
  float* out = (float*)d_out;

  char* ws = (char*)d_ws;
  short* xbf  = (short*)(ws);
  short* hbf  = (short*)(ws + 1048576);
  short* hnbf = (short*)(ws + 3145728);
  float* gi   = (float*)(ws + 5242880);
  float* gh   = (float*)(ws + 17825792);

  prep_kernel<<<1536, 256, 0, stream>>>(idx, hid, emb, xbf, hbf);
  gru_gemms_kernel<<<192, 512, 0, stream>>>(xbf, hbf, W_ih, W_hh, b_ih, b_hh, gi, gh);
  gates_kernel<<<1024, 256, 0, stream>>>(gi, gh, hid, out + (size_t)512 * 32000, hnbf);
  // 500 blocks x BN=64: W read once; ~2 blocks/CU
  logits_kernel<<<500, 512, 0, stream>>>(hnbf, fc_W, fc_b, out);
}

// Round 12
// 205.517 us; speedup vs baseline: 1.4775x; 1.3414x over previous
//
#include <hip/hip_runtime.h>
#include <hip/hip_bf16.h>

typedef __attribute__((ext_vector_type(8))) short short8;
typedef __attribute__((ext_vector_type(4))) short short4v;
typedef __attribute__((ext_vector_type(4))) float f32x4;

__device__ __forceinline__ short f2bf(float f) {
  union { __hip_bfloat16 h; short s; } u;
  u.h = __float2bfloat16(f);
  return u.s;
}

// async 16B global->LDS DMA: LDS dst = wave-uniform base + lane*16 (m104);
// global src per-lane.
__device__ __forceinline__ void gll16(const void* g, void* l) {
  __builtin_amdgcn_global_load_lds(
      (const __attribute__((address_space(1))) void*)g,
      (__attribute__((address_space(3))) void*)l, 16, 0, 0);
}

#define SCHED_FENCE() __builtin_amdgcn_sched_barrier(0)
#define EPS 68   // epilogue f32 row stride

// C[512, N] = A_bf16[512, K] * W_f32[N, K]^T + bias.  BN=64, BK=32.
// 8 waves; wave w owns rows [w*64..w*64+64); waves share the W panel.
// BOTH A and W stream via global_load_lds (vmcnt queue = DMA only; a wait
// for one never prematurely drains the other -- the R11 flaw).
// Rings: A 3 slots (32KB each), W 4 slots (8KB each) -> LDS 128KB.
// Per iter b: wait vmcnt(6) [drains A(b)+W(b), keeps W(b+1),A(b+1),W(b+2)];
// raw s_barrier; issue A(b+2) -> slot (b-1)%3, W(b+3) -> slot (b-1)&3
// (both proven consumed by this barrier); consume(b).
// Flight: W = 3 iters, A = 2 iters. Tail: vmcnt(5) at NT-2, (0) at NT-1.
// Source-swizzles (DMA writes LDS linearly, m173):
//   A [512][4x16B]: phys p <- src p^(row&3);  read phys = lq^(l16&3)
//   W [64][8x16B]:  phys p <- src p^(row&7);  read phys = (2lq+d)^(l16&7)
template<int K>
__device__ __forceinline__ void gemm_pipe(
    const short* __restrict__ A,
    const float* __restrict__ W,
    const float* __restrict__ bias,
    float* __restrict__ C,
    int N, int n0, char* smem)
{
  constexpr int NT = K / 32;
  char* Abase = smem;              // 3 x 32768
  char* Wbase = smem + 98304;     // 4 x 8192

  const int t   = threadIdx.x;
  const int w   = t >> 6;
  const int l   = t & 63;
  const int l16 = l & 15;
  const int lq  = l >> 4;

  f32x4 acc[4][4];
  #pragma unroll
  for (int i = 0; i < 4; ++i)
    #pragma unroll
    for (int j = 0; j < 4; ++j) {
      f32x4 z = {0.f, 0.f, 0.f, 0.f};
      acc[i][j] = z;
    }

  // A DMA: op j covers rows w*64 + j*16 + (l>>2), phys slot l&3,
  // source slot (l&3)^((l>>2)&3)  [row&3 == (l>>2)&3]
  const short* asrc = A + (size_t)(w * 64 + (l >> 2)) * K
                        + (((l & 3) ^ ((l >> 2) & 3)) << 3);
  // W DMA: wave op covers rows w*8 + (l>>3), phys slot l&7,
  // source slot (l&7)^(l>>3)  [row&7 == l>>3]
  const float* wsrc = W + (size_t)(n0 + w * 8 + (l >> 3)) * K
                        + (((l & 7) ^ (l >> 3)) << 2);

  auto issueA = [&](int bi, int slot) {
    char* d = Abase + slot * 32768 + w * 4096;
    const int kb = bi << 5;
    #pragma unroll
    for (int j = 0; j < 4; ++j)
      gll16(asrc + (size_t)j * 16 * K + kb, d + j * 1024);
  };
  auto issueW = [&](int bi) {
    gll16(wsrc + (bi << 5), Wbase + (bi & 3) * 8192 + w * 1024);
  };
  auto consume = [&](int bi, int slot) {
    const char* ab = Abase + slot * 32768;
    const char* wb = Wbase + (bi & 3) * 8192;
    short8 a[4];
    #pragma unroll
    for (int mf = 0; mf < 4; ++mf)
      a[mf] = *(const short8*)(ab + (w * 64 + mf * 16 + l16) * 64
                                  + ((lq ^ (l16 & 3)) << 4));
    const int x = l16 & 7;
    #pragma unroll
    for (int nf = 0; nf < 4; ++nf) {
      const int row = nf * 16 + l16;
      f32x4 u = *(const f32x4*)(wb + row * 128 + (((2 * lq)     ^ x) << 4));
      f32x4 v = *(const f32x4*)(wb + row * 128 + (((2 * lq + 1) ^ x) << 4));
      short8 bb;
      #pragma unroll
      for (int i = 0; i < 4; ++i) { bb[i] = f2bf(u[i]); bb[i + 4] = f2bf(v[i]); }
      #pragma unroll
      for (int mf = 0; mf < 4; ++mf)
        acc[mf][nf] = __builtin_amdgcn_mfma_f32_16x16x32_bf16(a[mf], bb, acc[mf][nf], 0, 0, 0);
    }
  };

  // prologue (queue order matters): [A0, W0, A1, W1, W2]
  issueA(0, 0); issueW(0); issueA(1, 1); issueW(1); issueW(2);

  int sc = 0;                       // b % 3 (consume slot)
  int si = 2;                       // (b+2) % 3 (issue slot)
  for (int b = 0; b < NT; ++b) {
    if (b < NT - 2)       { asm volatile("s_waitcnt vmcnt(6)" ::: "memory"); }
    else if (b == NT - 2) { asm volatile("s_waitcnt vmcnt(5)" ::: "memory"); }
    else                  { asm volatile("s_waitcnt vmcnt(0)" ::: "memory"); }
    SCHED_FENCE();
    __builtin_amdgcn_s_barrier();   // bundle b fully landed (all waves)
    SCHED_FENCE();
    if (b + 2 < NT) issueA(b + 2, si);
    if (b + 3 < NT) issueW(b + 3);
    SCHED_FENCE();
    consume(b, sc);
    sc = (sc == 2) ? 0 : sc + 1;
    si = (si == 2) ? 0 : si + 1;
  }
  __syncthreads();                   // before aliasing LDS for epilogue

  // ---- epilogue: per-wave LDS transpose -> full-line f32x4 stores ----
  // acc layout: col = nf*16 + l16, row = mf*16 + lq*4 + r  [m89]
  float bvv[4];
  #pragma unroll
  for (int nf = 0; nf < 4; ++nf) bvv[nf] = bias[n0 + nf * 16 + l16];

  float* ep = (float*)(smem) + w * 16 * EPS;
  const int rr = lq;
  const int cc = l16 * 4;
  #pragma unroll
  for (int mf = 0; mf < 4; ++mf) {
    #pragma unroll
    for (int nf = 0; nf < 4; ++nf)
      #pragma unroll
      for (int r = 0; r < 4; ++r)
        ep[(lq * 4 + r) * EPS + nf * 16 + l16] = acc[mf][nf][r] + bvv[nf];
    #pragma unroll
    for (int i = 0; i < 4; ++i) {
      f32x4 vv = *(const f32x4*)&ep[(i * 4 + rr) * EPS + cc];
      *(f32x4*)&C[(size_t)(w * 64 + mf * 16 + i * 4 + rr) * N + n0 + cc] = vv;
    }
  }
}

__global__ __launch_bounds__(512, 2) void gru_gemms_kernel(
    const short* __restrict__ xbf, const short* __restrict__ hbf,
    const float* __restrict__ W_ih, const float* __restrict__ W_hh,
    const float* __restrict__ b_ih, const float* __restrict__ b_hh,
    float* __restrict__ gi, float* __restrict__ gh)
{
  __shared__ __align__(16) char smem[131072];
  const bool second = blockIdx.x >= 96;
  const int nb = second ? (int)blockIdx.x - 96 : (int)blockIdx.x;
  if (second)
    gemm_pipe<2048>(hbf, W_hh, b_hh, gh, 6144, nb * 64, smem);
  else
    gemm_pipe<1024>(xbf, W_ih, b_ih, gi, 6144, nb * 64, smem);
}

__global__ __launch_bounds__(512, 2) void logits_kernel(
    const short* __restrict__ hnbf, const float* __restrict__ fc_W,
    const float* __restrict__ fc_b, float* __restrict__ out)
{
  __shared__ __align__(16) char smem[131072];
  gemm_pipe<2048>(hnbf, fc_W, fc_b, out, 32000, (int)blockIdx.x * 64, smem);
}

__global__ void prep_kernel(const int* __restrict__ idx,
                            const float* __restrict__ hid,
                            const float* __restrict__ emb,
                            short* __restrict__ xbf, short* __restrict__ hbf)
{
  int i = blockIdx.x * blockDim.x + threadIdx.x;
  const int NX = 512 * 1024 / 4;
  const int NH = 512 * 2048 / 4;
  if (i < NX) {
    int b = i >> 8;
    int c = (i & 255) << 2;
    int row = idx[b];
    f32x4 v = *(const f32x4*)(emb + (size_t)row * 1024 + c);
    short4v o;
    #pragma unroll
    for (int j = 0; j < 4; ++j) o[j] = f2bf(v[j]);
    *(short4v*)(xbf + (size_t)b * 1024 + c) = o;
  } else if (i < NX + NH) {
    int j2 = i - NX;
    f32x4 v = *(const f32x4*)(hid + (size_t)j2 * 4);
    short4v o;
    #pragma unroll
    for (int j = 0; j < 4; ++j) o[j] = f2bf(v[j]);
    *(short4v*)(hbf + (size_t)j2 * 4) = o;
  }
}

__global__ void gates_kernel(const float* __restrict__ gi,
                             const float* __restrict__ gh,
                             const float* __restrict__ hid,
                             float* __restrict__ hnew,
                             short* __restrict__ hnbf)
{
  int i = blockIdx.x * blockDim.x + threadIdx.x;
  int b = i >> 9;
  int c = (i & 511) << 2;
  size_t gbase = (size_t)b * 6144 + c;
  f32x4 gir = *(const f32x4*)(gi + gbase);
  f32x4 giz = *(const f32x4*)(gi + gbase + 2048);
  f32x4 gin = *(const f32x4*)(gi + gbase + 4096);
  f32x4 ghr = *(const f32x4*)(gh + gbase);
  f32x4 ghz = *(const f32x4*)(gh + gbase + 2048);
  f32x4 ghn = *(const f32x4*)(gh + gbase + 4096);
  f32x4 hv  = *(const f32x4*)(hid + (size_t)b * 2048 + c);
  f32x4 hn;
  short4v hb;
  #pragma unroll
  for (int j = 0; j < 4; ++j) {
    float r = 1.f / (1.f + __expf(-(gir[j] + ghr[j])));
    float z = 1.f / (1.f + __expf(-(giz[j] + ghz[j])));
    float n = tanhf(gin[j] + r * ghn[j]);
    float o = (1.f - z) * n + z * hv[j];
    hn[j] = o;
    hb[j] = f2bf(o);
  }
  *(f32x4*)(hnew + (size_t)b * 2048 + c) = hn;
  *(short4v*)(hnbf + (size_t)b * 2048 + c) = hb;
}

extern "C" void kernel_launch(void* const* d_in, const int* in_sizes, int n_in,
                              void* d_out, int out_size, void* d_ws, size_t ws_size,
                              hipStream_t stream)
{
  const int*   idx   = (const int*)d_in[0];
  const float* hid   = (const float*)d_in[1];
  const float* emb   = (const float*)d_in[2];
  const float* W_ih  = (const float*)d_in[3];
  const float* W_hh  = (const float*)d_in[4];
  const float* b_ih  = (const float*)d_in[5];
  const float* b_hh  = (const float*)d_in[6];
  const float* fc_W  = (const float*)d_in[7];
  const float* fc_b  = (const float*)d_in[8];
  float* out = (float*)d_out;

  char* ws = (char*)d_ws;
  short* xbf  = (short*)(ws);
  short* hbf  = (short*)(ws + 1048576);
  short* hnbf = (short*)(ws + 3145728);
  float* gi   = (float*)(ws + 5242880);
  float* gh   = (float*)(ws + 17825792);

  prep_kernel<<<1536, 256, 0, stream>>>(idx, hid, emb, xbf, hbf);
  gru_gemms_kernel<<<192, 512, 0, stream>>>(xbf, hbf, W_ih, W_hh, b_ih, b_hh, gi, gh);
  gates_kernel<<<1024, 256, 0, stream>>>(gi, gh, hid, out + (size_t)512 * 32000, hnbf);
  logits_kernel<<<500, 512, 0, stream>>>(hnbf, fc_W, fc_b, out);
}